// Round 6
// baseline (172.056 us; speedup 1.0000x reference)
//
#include <hip/hip_runtime.h>
#include <hip/hip_bf16.h>

// ON-LSTM cell fused, R6: 256x256 tile on the 32x32x16 bf16 MFMA pipe.
// 4 phases per K-tile (phase = k-step, 8 independent MFMAs), B-frag
// prefetch one phase ahead (bfr1/bfr2), counted lgkmcnt(4) at every
// barrier, vmcnt(4)@p2 / vmcnt(0)@p3, stages {B(t+1),A(t+1).h0}@p0,
// A(t+1).h1@p1. Waves 4M x 2N; gate-stride-32 packing keeps all 4 gates
// of (b,h) lane-local for the fused cumsoftmax/LSTM epilogue.

#define B_ROWS 8192
#define IN_DIM 1024
#define H_DIM  1024
#define NCHUNK 16
#define K_TOT  2048

#define BM   256
#define BN   256
#define BK   64
#define NKT  (K_TOT / BK)   // 32 K-tiles
#define THREADS 512

#define A_PACK_BYTES ((size_t)B_ROWS * K_TOT * 2)        // 32 MiB
#define W_PACK_BYTES ((size_t)16 * 256 * K_TOT * 2)      // 16 MiB

typedef __attribute__((ext_vector_type(4)))  float f32x4;
typedef __attribute__((ext_vector_type(16))) float f32x16;
typedef __bf16 bf16x8 __attribute__((ext_vector_type(8)));

__device__ __forceinline__ float sigmoidf_(float x) {
    return 1.0f / (1.0f + __expf(-x));
}
__device__ __forceinline__ float tanhf_(float x) {
    float e = __expf(-2.0f * fabsf(x));
    float t = (1.0f - e) / (1.0f + e);
    return copysignf(t, x);
}

__device__ __forceinline__ void gload16(const __bf16* gsrc, __bf16* lds_dst) {
    __builtin_amdgcn_global_load_lds(
        (const __attribute__((address_space(1))) unsigned int*)gsrc,
        (__attribute__((address_space(3))) unsigned int*)lds_dst, 16, 0, 0);
}

__device__ __forceinline__ bf16x8 cvt8(f32x4 v0, f32x4 v1) {
    bf16x8 o;
    o[0] = (__bf16)v0.x; o[1] = (__bf16)v0.y; o[2] = (__bf16)v0.z; o[3] = (__bf16)v0.w;
    o[4] = (__bf16)v1.x; o[5] = (__bf16)v1.y; o[6] = (__bf16)v1.z; o[7] = (__bf16)v1.w;
    return o;
}

// ---- fused pack: blocks [0,8192) pack A rows; [8192,12288) pack W rows ----
// A: [x|hx] -> bf16 Abf[8192][2048].
// W col n of block bh: gate g=(n>>5)&3, h j=(n>>7)*32+(n&31),
//    weight row g*1024 + bh*64 + j -> Wp[bh][n][2048].
__global__ __launch_bounds__(256)
void pack_AW(const float* __restrict__ x, const float* __restrict__ hx,
             const float* __restrict__ W_ih, const float* __restrict__ W_hh,
             __bf16* __restrict__ Abf, __bf16* __restrict__ Wp)
{
    const int bid = blockIdx.x;
    const int c8  = threadIdx.x << 3;
    if (bid < B_ROWS) {
        const float* src = (c8 < IN_DIM)
            ? (x  + (size_t)bid * IN_DIM + c8)
            : (hx + (size_t)bid * IN_DIM + (c8 - IN_DIM));
        f32x4 v0 = *reinterpret_cast<const f32x4*>(src);
        f32x4 v1 = *reinterpret_cast<const f32x4*>(src + 4);
        *reinterpret_cast<bf16x8*>(Abf + (size_t)bid * K_TOT + c8) = cvt8(v0, v1);
    } else {
        const int r  = bid - B_ROWS;       // 0..4095
        const int bh = r >> 8;
        const int n  = r & 255;
        const int g  = (n >> 5) & 3;
        const int j  = (n >> 7) * 32 + (n & 31);
        const int wr = g * H_DIM + bh * 64 + j;
        const float* src = (c8 < IN_DIM)
            ? (W_ih + (size_t)wr * IN_DIM + c8)
            : (W_hh + (size_t)wr * IN_DIM + (c8 - IN_DIM));
        f32x4 v0 = *reinterpret_cast<const f32x4*>(src);
        f32x4 v1 = *reinterpret_cast<const f32x4*>(src + 4);
        *reinterpret_cast<bf16x8*>(Wp + (size_t)r * K_TOT + c8) = cvt8(v0, v1);
    }
}

// stage one 128x64 half-tile: 2 x global_load_lds(16B)/thread, linear LDS
// dest, inverse-swizzled global source.
__device__ __forceinline__ void stage_half(const __bf16* __restrict__ gbase, int kb,
                                           __bf16* lbase, int row0, int tid) {
    #pragma unroll
    for (int i = 0; i < 2; ++i) {
        int e   = i * 4096 + tid * 8;
        int row = row0 + (e >> 6);
        int kd  = e & 63;
        gload16(gbase + (size_t)row * K_TOT + kb + (kd ^ ((row & 7) << 3)), lbase + e);
    }
}

#define SWZ(r, k) ((r) * 64 + ((k) ^ (((r) & 7) << 3)))

// A frags for k-step q: row = wrow + mt*32 + c32, k = q*16 + khi8 .. +8
#define LDA2(As, q) { \
    int ar = wrow + c32; \
    af[0] = *reinterpret_cast<const bf16x8*>(&(As)[SWZ(ar,      (q) * 16 + khi8)]); \
    af[1] = *reinterpret_cast<const bf16x8*>(&(As)[SWZ(ar + 32, (q) * 16 + khi8)]); }

// B frags (4 n-tiles) for k-step ks into dst
#define LDB4(Bs, dst, ks) { \
    _Pragma("unroll") \
    for (int n = 0; n < 4; ++n) { \
        int br = wcol + n * 32 + c32; \
        dst[n] = *reinterpret_cast<const bf16x8*>(&(Bs)[SWZ(br, (ks) * 16 + khi8)]); } }

// counted waits: lgkm(4) keeps this phase's 4 B-prefetch reads in flight,
// retires the frags this phase's MFMA consumes.
#define WBARL \
    asm volatile("s_waitcnt lgkmcnt(4)" ::: "memory"); \
    __builtin_amdgcn_sched_barrier(0); \
    __builtin_amdgcn_s_barrier(); \
    __builtin_amdgcn_sched_barrier(0);

#define WBARLV4 \
    asm volatile("s_waitcnt vmcnt(4) lgkmcnt(4)" ::: "memory"); \
    __builtin_amdgcn_sched_barrier(0); \
    __builtin_amdgcn_s_barrier(); \
    __builtin_amdgcn_sched_barrier(0);

#define WBARLV0 \
    asm volatile("s_waitcnt vmcnt(0) lgkmcnt(4)" ::: "memory"); \
    __builtin_amdgcn_sched_barrier(0); \
    __builtin_amdgcn_s_barrier(); \
    __builtin_amdgcn_sched_barrier(0);

// 8 independent 32x32x16 MFMAs (one k-step, all 8 accs)
#define MF32(bsrc) { \
    __builtin_amdgcn_s_setprio(1); \
    _Pragma("unroll") \
    for (int n = 0; n < 4; ++n) { \
        acc[0][n] = __builtin_amdgcn_mfma_f32_32x32x16_bf16(af[0], bsrc[n], acc[0][n], 0, 0, 0); \
        acc[1][n] = __builtin_amdgcn_mfma_f32_32x32x16_bf16(af[1], bsrc[n], acc[1][n], 0, 0, 0); \
    } \
    __builtin_amdgcn_s_setprio(0); \
    __builtin_amdgcn_sched_barrier(0); \
}

__global__ __launch_bounds__(THREADS, 2)
void onlstm_gemm32(const __bf16* __restrict__ Abf, const __bf16* __restrict__ Wp,
                   const float* __restrict__ cx,
                   const float* __restrict__ input_floor,
                   const float* __restrict__ forget_floor,
                   const float* __restrict__ b_ih, const float* __restrict__ b_hh,
                   float* __restrict__ out)
{
    __shared__ __align__(16) __bf16 lds[65536];          // 128 KiB
    __shared__ float ci_s[BM], cf_s[BM], bias_s[BN];

    const int tid = threadIdx.x;
    // XCD swizzle: xcd owns 4 bm-panels x all 16 bh -> A L2-resident per XCD
    const int n0  = blockIdx.x;
    const int bm  = (n0 & 7) * 4 + ((n0 >> 3) & 3);   // 0..31
    const int bh  = n0 >> 5;                          // 0..15
    const int h0  = bh * 64;
    const int nc  = bh;

    // ---- prologue: bias + per-row cumulative-softmax master gates ----
    if (tid < BM) {
        {
            int g = (tid >> 5) & 3;
            int j = (tid >> 7) * 32 + (tid & 31);
            int wrr = g * H_DIM + h0 + j;
            bias_s[tid] = b_ih[wrr] + b_hh[wrr];
        }
        int b = bm * BM + tid;
        const int off = (nc < 8) ? 0 : 8;
        const int ic  = (nc < 8) ? nc : (nc - 8);
        const float* pin = input_floor  + (size_t)b * NCHUNK + off;
        const float* pfg = forget_floor + (size_t)b * NCHUNK + off;
        float vi[8], vf[8];
        float mi = -1e30f, mf = -1e30f;
        #pragma unroll
        for (int t = 0; t < 8; ++t) {
            vi[t] = pin[t]; vf[t] = pfg[t];
            mi = fmaxf(mi, vi[t]); mf = fmaxf(mf, vf[t]);
        }
        float si = 0.f, sf = 0.f;
        #pragma unroll
        for (int t = 0; t < 8; ++t) {
            vi[t] = __expf(vi[t] - mi); vf[t] = __expf(vf[t] - mf);
            si += vi[t]; sf += vf[t];
        }
        float pi = 0.f, pf = 0.f;
        #pragma unroll
        for (int t = 0; t < 8; ++t) { if (t <= ic) { pi += vi[t]; pf += vf[t]; } }
        float suf_i = si - pi + vi[ic];
        float suf_f = sf - pf + vf[ic];
        float civ, cfv;
        if (nc < 8) { civ = pi / si;    cfv = suf_f / sf; }
        else        { civ = suf_i / si; cfv = pf / sf;    }
        ci_s[tid] = civ; cf_s[tid] = cfv;
    }

    const __bf16* Arow = Abf + (size_t)(bm * BM) * K_TOT;
    const __bf16* Wblk = Wp  + (size_t)bh * 256 * K_TOT;
    __bf16* const A0p = lds;
    __bf16* const B0p = lds + 16384;
    __bf16* const A1p = lds + 32768;
    __bf16* const B1p = lds + 49152;

    const int l    = tid & 63;
    const int wid  = tid >> 6;        // 0..7
    const int wrw  = wid >> 1;        // 0..3  (M)
    const int wc   = wid & 1;         // 0..1  (N)
    const int c32  = l & 31;
    const int khi8 = (l >> 5) * 8;
    const int wrow = wrw * 64;
    const int wcol = wc * 128;

    // prologue staging: t0.B, t0.A (B(1)/A(1) staged inside tile 0 phases)
    stage_half(Wblk, 0, B0p,        0,   tid);
    stage_half(Wblk, 0, B0p + 8192, 128, tid);
    stage_half(Arow, 0, A0p,        0,   tid);
    stage_half(Arow, 0, A0p + 8192, 128, tid);
    asm volatile("s_waitcnt vmcnt(0) lgkmcnt(0)" ::: "memory");
    __builtin_amdgcn_s_barrier();
    asm volatile("" ::: "memory");

    f32x16 acc[2][4];
    #pragma unroll
    for (int i = 0; i < 2; ++i)
        #pragma unroll
        for (int j = 0; j < 4; ++j) acc[i][j] = (f32x16)(0.0f);
    bf16x8 af[2];
    bf16x8 bfr1[4], bfr2[4];

    // pipeline seed: B(0) k0 into bfr1
    LDB4(B0p, bfr1, 0);

    #pragma unroll 1
    for (int it = 0; it < NKT / 2; ++it) {
        const int t = 2 * it;
        // ======== K-tile t: cur = A0p/B0p, nxt = A1p/B1p ========
        // p0: consume bfr1(k0); prefetch bfr2(k1); stage B(t+1) full + A(t+1).h0
        LDA2(A0p, 0);
        LDB4(B0p, bfr2, 1);
        stage_half(Wblk, ((t + 1) & 31) * BK, B1p,        0,   tid);
        stage_half(Wblk, ((t + 1) & 31) * BK, B1p + 8192, 128, tid);
        stage_half(Arow, ((t + 1) & 31) * BK, A1p,        0,   tid);
        WBARL;   MF32(bfr1);
        // p1: consume bfr2(k1); prefetch bfr1(k2); stage A(t+1).h1
        LDA2(A0p, 1);
        LDB4(B0p, bfr1, 2);
        stage_half(Arow, ((t + 1) & 31) * BK, A1p + 8192, 128, tid);
        WBARL;   MF32(bfr2);
        // p2: consume bfr1(k2); prefetch bfr2(k3); vmcnt(4) retires B(t+1)
        LDA2(A0p, 2);
        LDB4(B0p, bfr2, 3);
        WBARLV4; MF32(bfr1);
        // p3: consume bfr2(k3); prefetch bfr1(k0 of t+1); vmcnt(0) retires A(t+1)
        LDA2(A0p, 3);
        LDB4(B1p, bfr1, 0);
        WBARLV0; MF32(bfr2);
        // ======== K-tile t+1: cur = A1p/B1p, nxt = A0p/B0p ========
        LDA2(A1p, 0);
        LDB4(B1p, bfr2, 1);
        stage_half(Wblk, ((t + 2) & 31) * BK, B0p,        0,   tid);
        stage_half(Wblk, ((t + 2) & 31) * BK, B0p + 8192, 128, tid);
        stage_half(Arow, ((t + 2) & 31) * BK, A0p,        0,   tid);
        WBARL;   MF32(bfr1);
        LDA2(A1p, 1);
        LDB4(B1p, bfr1, 2);
        stage_half(Arow, ((t + 2) & 31) * BK, A0p + 8192, 128, tid);
        WBARL;   MF32(bfr2);
        LDA2(A1p, 2);
        LDB4(B1p, bfr2, 3);
        WBARLV4; MF32(bfr1);
        LDA2(A1p, 3);
        LDB4(B0p, bfr1, 0);
        WBARLV0; MF32(bfr2);
    }
    asm volatile("s_waitcnt vmcnt(0) lgkmcnt(0)" ::: "memory");

    // ---- epilogue: all 4 gates of (b,h) lane-local (n-tile = gate) ----
    // C 32x32 layout: col = lane&31, row = (reg&3) + 8*(reg>>2) + 4*(lane>>5)
    const size_t CY_OFF = (size_t)B_ROWS * H_DIM;
    const int hcol = h0 + wc * 32 + c32;
    const int rbase = (l >> 5) * 4;
    #pragma unroll
    for (int mt = 0; mt < 2; ++mt) {
        #pragma unroll
        for (int reg = 0; reg < 16; ++reg) {
            int r32 = (reg & 3) + 8 * (reg >> 2) + rbase;
            int rt  = wrow + mt * 32 + r32;
            int b   = bm * BM + rt;
            float civ = ci_s[rt], cfv = cf_s[rt];
            float ovl = cfv * civ;
            float og = acc[mt][0][reg] + bias_s[wcol + c32];
            float cg = acc[mt][1][reg] + bias_s[wcol + 32 + c32];
            float ig = acc[mt][2][reg] + bias_s[wcol + 64 + c32];
            float fg = acc[mt][3][reg] + bias_s[wcol + 96 + c32];
            float i_s = sigmoidf_(ig);
            float f_s = sigmoidf_(fg);
            float c_t = tanhf_(cg);
            float o_s = sigmoidf_(og);
            float fq = f_s * ovl + (cfv - ovl);
            float iq = i_s * ovl + (civ - ovl);
            float cxv = cx[(size_t)b * H_DIM + hcol];
            float cyv = fq * cxv + iq * c_t;
            float hyv = o_s * tanhf_(cyv);
            out[(size_t)b * H_DIM + hcol] = hyv;
            out[CY_OFF + (size_t)b * H_DIM + hcol] = cyv;
        }
    }
}

extern "C" void kernel_launch(void* const* d_in, const int* in_sizes, int n_in,
                              void* d_out, int out_size, void* d_ws, size_t ws_size,
                              hipStream_t stream) {
    const float* x            = (const float*)d_in[0];
    const float* hx           = (const float*)d_in[1];
    const float* cx           = (const float*)d_in[2];
    const float* input_floor  = (const float*)d_in[3];
    const float* forget_floor = (const float*)d_in[4];
    const float* W_ih         = (const float*)d_in[5];
    const float* b_ih         = (const float*)d_in[6];
    const float* W_hh         = (const float*)d_in[7];
    const float* b_hh         = (const float*)d_in[8];
    float* out = (float*)d_out;

    __bf16* Abf = (__bf16*)d_ws;
    __bf16* Wp  = (__bf16*)((char*)d_ws + A_PACK_BYTES);
    pack_AW<<<B_ROWS + 16 * 256, 256, 0, stream>>>(x, hx, W_ih, W_hh, Abf, Wp);
    onlstm_gemm32<<<512, THREADS, 0, stream>>>(
        Abf, Wp, cx, input_floor, forget_floor, b_ih, b_hh, out);
}

// Round 7
// 156.031 us; speedup vs baseline: 1.1027x; 1.1027x over previous
//
#include <hip/hip_runtime.h>
#include <hip/hip_bf16.h>

// ON-LSTM cell fused, R7: R5's 256x256 16x16x32 schedule, de-synchronized:
// MFMA clusters run BEFORE each barrier (compiler emits fine-grained lgkmcnt
// instead of forced lgkmcnt(0) drains), only 2 barriers per K-tile:
//   p0: [LDB 8 + LDA(0) 4 reads; stage A(t+1)x2; MF(0); BAR]   <- publishes LDB drain, protects B re-stage
//   p1: [LDA(1); stage B(t+2)h0; MF(1)]                        <- no barrier
//   p2: [LDA(2); stage B(t+2)h1; MF(2)]                        <- no barrier
//   p3: [LDA(3); MF(3); vmcnt(4); BAR]                         <- publishes A(t+1)/B(t+1) stage completion
// Race audit:
//  - B_c restaged at p1/p2: all waves drained LDB(B_c) inside MF(0) (operand
//    lgkm waits) before p0's barrier. Drift p1..p3 is safe (next conflicting
//    write is after p3's barrier).
//  - A_n staged at p0: tile t-1's LDA reads drained by MF(3) + p3 barrier.
//  - p0(t+1) reads A(t+1)/B(t+1): vmcnt(4) at p3(t) retires them per-wave
//    (outstanding there = B(t+1)4 + A(t+1)4 + B(t+2)4 = 12 -> <=4), barrier
//    publishes across waves.

#define B_ROWS 8192
#define IN_DIM 1024
#define H_DIM  1024
#define NCHUNK 16
#define K_TOT  2048

#define BM   256
#define BN   256
#define BK   64
#define NKT  (K_TOT / BK)   // 32 K-tiles
#define THREADS 512

#define A_PACK_BYTES ((size_t)B_ROWS * K_TOT * 2)        // 32 MiB
#define W_PACK_BYTES ((size_t)16 * 256 * K_TOT * 2)      // 16 MiB

typedef __attribute__((ext_vector_type(4))) float  f32x4;
typedef __bf16 bf16x8 __attribute__((ext_vector_type(8)));

__device__ __forceinline__ float sigmoidf_(float x) {
    return 1.0f / (1.0f + __expf(-x));
}
__device__ __forceinline__ float tanhf_(float x) {
    float e = __expf(-2.0f * fabsf(x));
    float t = (1.0f - e) / (1.0f + e);
    return copysignf(t, x);
}

__device__ __forceinline__ void gload16(const __bf16* gsrc, __bf16* lds_dst) {
    __builtin_amdgcn_global_load_lds(
        (const __attribute__((address_space(1))) unsigned int*)gsrc,
        (__attribute__((address_space(3))) unsigned int*)lds_dst, 16, 0, 0);
}

__device__ __forceinline__ bf16x8 cvt8(f32x4 v0, f32x4 v1) {
    bf16x8 o;
    o[0] = (__bf16)v0.x; o[1] = (__bf16)v0.y; o[2] = (__bf16)v0.z; o[3] = (__bf16)v0.w;
    o[4] = (__bf16)v1.x; o[5] = (__bf16)v1.y; o[6] = (__bf16)v1.z; o[7] = (__bf16)v1.w;
    return o;
}

// ---- fused pack: blocks [0,8192) pack A rows; [8192,12288) pack W rows ----
__global__ __launch_bounds__(256)
void pack_AW(const float* __restrict__ x, const float* __restrict__ hx,
             const float* __restrict__ W_ih, const float* __restrict__ W_hh,
             __bf16* __restrict__ Abf, __bf16* __restrict__ Wp)
{
    const int bid = blockIdx.x;
    const int c8  = threadIdx.x << 3;
    if (bid < B_ROWS) {
        const float* src = (c8 < IN_DIM)
            ? (x  + (size_t)bid * IN_DIM + c8)
            : (hx + (size_t)bid * IN_DIM + (c8 - IN_DIM));
        f32x4 v0 = *reinterpret_cast<const f32x4*>(src);
        f32x4 v1 = *reinterpret_cast<const f32x4*>(src + 4);
        *reinterpret_cast<bf16x8*>(Abf + (size_t)bid * K_TOT + c8) = cvt8(v0, v1);
    } else {
        const int r  = bid - B_ROWS;       // 0..4095
        const int bh = r >> 8;
        const int n  = r & 255;
        const int g  = (n >> 4) & 3;
        const int j  = (n >> 6) * 16 + (n & 15);
        const int wr = g * H_DIM + bh * 64 + j;
        const float* src = (c8 < IN_DIM)
            ? (W_ih + (size_t)wr * IN_DIM + c8)
            : (W_hh + (size_t)wr * IN_DIM + (c8 - IN_DIM));
        f32x4 v0 = *reinterpret_cast<const f32x4*>(src);
        f32x4 v1 = *reinterpret_cast<const f32x4*>(src + 4);
        *reinterpret_cast<bf16x8*>(Wp + (size_t)r * K_TOT + c8) = cvt8(v0, v1);
    }
}

// stage one 128x64 half-tile: 2 x global_load_lds(16B)/thread, linear LDS
// dest, inverse-swizzled global source.
__device__ __forceinline__ void stage_half(const __bf16* __restrict__ gbase, int kb,
                                           __bf16* lbase, int row0, int tid) {
    #pragma unroll
    for (int i = 0; i < 2; ++i) {
        int e   = i * 4096 + tid * 8;
        int row = row0 + (e >> 6);
        int kd  = e & 63;
        gload16(gbase + (size_t)row * K_TOT + kb + (kd ^ ((row & 7) << 3)), lbase + e);
    }
}

#define SWZ(r, k) ((r) * 64 + ((k) ^ (((r) & 7) << 3)))

#define LDB(Bs) { \
    _Pragma("unroll") \
    for (int fn = 0; fn < 4; ++fn) { \
        int br = wcol + fn * 16 + lr; \
        bfr[fn][0] = *reinterpret_cast<const bf16x8*>(&(Bs)[SWZ(br, lh * 8)]); \
        bfr[fn][1] = *reinterpret_cast<const bf16x8*>(&(Bs)[SWZ(br, 32 + lh * 8)]); \
    } }

#define LDA(As, q) { \
    int ar = wrow + (q) * 32 + lr; \
    af[0][0] = *reinterpret_cast<const bf16x8*>(&(As)[SWZ(ar, lh * 8)]); \
    af[0][1] = *reinterpret_cast<const bf16x8*>(&(As)[SWZ(ar, 32 + lh * 8)]); \
    af[1][0] = *reinterpret_cast<const bf16x8*>(&(As)[SWZ(ar + 16, lh * 8)]); \
    af[1][1] = *reinterpret_cast<const bf16x8*>(&(As)[SWZ(ar + 16, 32 + lh * 8)]); \
    }

#define SB0 __builtin_amdgcn_sched_barrier(0)
#define BARRIER do { \
    asm volatile("" ::: "memory"); \
    __builtin_amdgcn_s_barrier(); \
    asm volatile("" ::: "memory"); \
} while (0)

// k-slice-outer ordering: 8 independent MFMAs between dependent same-acc pairs.
// No forced lgkm drain: compiler inserts fine-grained counted waits per operand.
#define MF(q) { \
    __builtin_amdgcn_s_setprio(1); \
    _Pragma("unroll") \
    for (int ks = 0; ks < 2; ++ks) { \
        _Pragma("unroll") \
        for (int fn = 0; fn < 4; ++fn) { \
            acc[2*(q)][fn]   = __builtin_amdgcn_mfma_f32_16x16x32_bf16(af[0][ks], bfr[fn][ks], acc[2*(q)][fn],   0,0,0); \
            acc[2*(q)+1][fn] = __builtin_amdgcn_mfma_f32_16x16x32_bf16(af[1][ks], bfr[fn][ks], acc[2*(q)+1][fn], 0,0,0); \
        } \
    } \
    __builtin_amdgcn_s_setprio(0); \
}

__global__ __launch_bounds__(THREADS, 2)
void onlstm_gemm8(const __bf16* __restrict__ Abf, const __bf16* __restrict__ Wp,
                  const float* __restrict__ cx,
                  const float* __restrict__ input_floor,
                  const float* __restrict__ forget_floor,
                  const float* __restrict__ b_ih, const float* __restrict__ b_hh,
                  float* __restrict__ out)
{
    __shared__ __align__(16) __bf16 lds[65536];          // 128 KiB
    __shared__ float ci_s[BM], cf_s[BM], bias_s[BN];

    const int tid = threadIdx.x;
    // XCD swizzle: xcd = n0&7 owns bm in [4*xcd, 4*xcd+4) x all 16 bh
    const int n0  = blockIdx.x;
    const int bm  = (n0 & 7) * 4 + ((n0 >> 3) & 3);   // 0..31
    const int bh  = n0 >> 5;                          // 0..15
    const int h0  = bh * 64;
    const int nc  = bh;

    // ---- prologue: bias + per-row cumulative-softmax master gates ----
    if (tid < BM) {
        {
            int g = (tid >> 4) & 3;
            int j = (tid >> 6) * 16 + (tid & 15);
            int wrr = g * H_DIM + h0 + j;
            bias_s[tid] = b_ih[wrr] + b_hh[wrr];
        }
        int b = bm * BM + tid;
        const int off = (nc < 8) ? 0 : 8;
        const int ic  = (nc < 8) ? nc : (nc - 8);
        const float* pin = input_floor  + (size_t)b * NCHUNK + off;
        const float* pfg = forget_floor + (size_t)b * NCHUNK + off;
        float vi[8], vf[8];
        float mi = -1e30f, mf = -1e30f;
        #pragma unroll
        for (int t = 0; t < 8; ++t) {
            vi[t] = pin[t]; vf[t] = pfg[t];
            mi = fmaxf(mi, vi[t]); mf = fmaxf(mf, vf[t]);
        }
        float si = 0.f, sf = 0.f;
        #pragma unroll
        for (int t = 0; t < 8; ++t) {
            vi[t] = __expf(vi[t] - mi); vf[t] = __expf(vf[t] - mf);
            si += vi[t]; sf += vf[t];
        }
        float pi = 0.f, pf = 0.f;
        #pragma unroll
        for (int t = 0; t < 8; ++t) { if (t <= ic) { pi += vi[t]; pf += vf[t]; } }
        float suf_i = si - pi + vi[ic];
        float suf_f = sf - pf + vf[ic];
        float civ, cfv;
        if (nc < 8) { civ = pi / si;    cfv = suf_f / sf; }
        else        { civ = suf_i / si; cfv = pf / sf;    }
        ci_s[tid] = civ; cf_s[tid] = cfv;
    }

    const __bf16* Arow = Abf + (size_t)(bm * BM) * K_TOT;
    const __bf16* Wblk = Wp  + (size_t)bh * 256 * K_TOT;
    __bf16* const A0p = lds;
    __bf16* const B0p = lds + 16384;
    __bf16* const A1p = lds + 32768;
    __bf16* const B1p = lds + 49152;

    // prologue staging: t0.A (A0p), t0.B (B0p), t1.B (B1p); t1.A staged at t0.p0
    stage_half(Arow, 0,  A0p,        0,   tid);
    stage_half(Arow, 0,  A0p + 8192, 128, tid);
    stage_half(Wblk, 0,  B0p,        0,   tid);
    stage_half(Wblk, 0,  B0p + 8192, 128, tid);
    stage_half(Wblk, BK, B1p,        0,   tid);
    stage_half(Wblk, BK, B1p + 8192, 128, tid);
    asm volatile("s_waitcnt lgkmcnt(0)" ::: "memory");   // ci/bias ds_writes done
    asm volatile("s_waitcnt vmcnt(4)"   ::: "memory");   // t0 complete, t1.B in flight
    __builtin_amdgcn_s_barrier();
    asm volatile("" ::: "memory");

    f32x4  acc[8][4];
    #pragma unroll
    for (int i = 0; i < 8; ++i)
        #pragma unroll
        for (int j = 0; j < 4; ++j) acc[i][j] = (f32x4){0.f, 0.f, 0.f, 0.f};
    bf16x8 af[2][2];
    bf16x8 bfr[4][2];

    const int l    = tid & 63;
    const int wid  = tid >> 6;        // 0..7
    const int wrw  = wid >> 2;        // 0..1  (M)
    const int wc   = wid & 3;         // 0..3  (N)
    const int lr   = l & 15;
    const int lh   = l >> 4;
    const int wrow = wrw * 128;
    const int wcol = wc * 64;

    #pragma unroll 1
    for (int it = 0; it < NKT / 2; ++it) {
        const int t = 2 * it;
        // ---- K-tile t (buf0) ----
        // p0
        LDB(B0p); LDA(A0p, 0);
        stage_half(Arow, ((t + 1) & 31) * BK, A1p,        0,   tid);   // (t+1).A0
        stage_half(Arow, ((t + 1) & 31) * BK, A1p + 8192, 128, tid);   // (t+1).A1
        SB0; MF(0); BARRIER;
        // p1
        LDA(A0p, 1);
        stage_half(Wblk, ((t + 2) & 31) * BK, B0p,        0,   tid);   // (t+2).B0
        SB0; MF(1); SB0;
        // p2
        LDA(A0p, 2);
        stage_half(Wblk, ((t + 2) & 31) * BK, B0p + 8192, 128, tid);   // (t+2).B1
        SB0; MF(2); SB0;
        // p3
        LDA(A0p, 3);
        SB0; MF(3);
        asm volatile("s_waitcnt vmcnt(4)" ::: "memory");
        BARRIER;
        // ---- K-tile t+1 (buf1) ----
        // p0
        LDB(B1p); LDA(A1p, 0);
        stage_half(Arow, ((t + 2) & 31) * BK, A0p,        0,   tid);   // (t+2).A0
        stage_half(Arow, ((t + 2) & 31) * BK, A0p + 8192, 128, tid);   // (t+2).A1
        SB0; MF(0); BARRIER;
        // p1
        LDA(A1p, 1);
        stage_half(Wblk, ((t + 3) & 31) * BK, B1p,        0,   tid);   // (t+3).B0
        SB0; MF(1); SB0;
        // p2
        LDA(A1p, 2);
        stage_half(Wblk, ((t + 3) & 31) * BK, B1p + 8192, 128, tid);   // (t+3).B1
        SB0; MF(2); SB0;
        // p3
        LDA(A1p, 3);
        SB0; MF(3);
        asm volatile("s_waitcnt vmcnt(4)" ::: "memory");
        BARRIER;
    }
    asm volatile("s_waitcnt vmcnt(0) lgkmcnt(0)" ::: "memory");
    __builtin_amdgcn_s_barrier();

    // ---- epilogue: all 4 gates of (b,h) lane-local (fn = gate) ----
    const size_t CY_OFF = (size_t)B_ROWS * H_DIM;
    const int hcol = h0 + wc * 16 + lr;
    #pragma unroll
    for (int m = 0; m < 8; ++m) {
        #pragma unroll
        for (int r = 0; r < 4; ++r) {
            int rt = wrow + m * 16 + lh * 4 + r;
            int b  = bm * BM + rt;
            float civ = ci_s[rt], cfv = cf_s[rt];
            float ovl = cfv * civ;
            float og = acc[m][0][r] + bias_s[wcol + lr];
            float cg = acc[m][1][r] + bias_s[wcol + 16 + lr];
            float ig = acc[m][2][r] + bias_s[wcol + 32 + lr];
            float fg = acc[m][3][r] + bias_s[wcol + 48 + lr];
            float i_s = sigmoidf_(ig);
            float f_s = sigmoidf_(fg);
            float c_t = tanhf_(cg);
            float o_s = sigmoidf_(og);
            float fq = f_s * ovl + (cfv - ovl);
            float iq = i_s * ovl + (civ - ovl);
            float cxv = cx[(size_t)b * H_DIM + hcol];
            float cyv = fq * cxv + iq * c_t;
            float hyv = o_s * tanhf_(cyv);
            out[(size_t)b * H_DIM + hcol] = hyv;
            out[CY_OFF + (size_t)b * H_DIM + hcol] = cyv;
        }
    }
}

extern "C" void kernel_launch(void* const* d_in, const int* in_sizes, int n_in,
                              void* d_out, int out_size, void* d_ws, size_t ws_size,
                              hipStream_t stream) {
    const float* x            = (const float*)d_in[0];
    const float* hx           = (const float*)d_in[1];
    const float* cx           = (const float*)d_in[2];
    const float* input_floor  = (const float*)d_in[3];
    const float* forget_floor = (const float*)d_in[4];
    const float* W_ih         = (const float*)d_in[5];
    const float* b_ih         = (const float*)d_in[6];
    const float* W_hh         = (const float*)d_in[7];
    const float* b_hh         = (const float*)d_in[8];
    float* out = (float*)d_out;

    __bf16* Abf = (__bf16*)d_ws;
    __bf16* Wp  = (__bf16*)((char*)d_ws + A_PACK_BYTES);
    pack_AW<<<B_ROWS + 16 * 256, 256, 0, stream>>>(x, hx, W_ih, W_hh, Abf, Wp);
    onlstm_gemm8<<<512, THREADS, 0, stream>>>(
        Abf, Wp, cx, input_floor, forget_floor, b_ih, b_hh, out);
}